// Round 1
// baseline (699.000 us; speedup 1.0000x reference)
//
#include <hip/hip_runtime.h>
#include <stdint.h>

#define N_  8
#define CK  128
#define CV  512
#define HW  900     // 30*30 queries
#define M_  7200    // 8*30*30 memory slots
#define QK_SCALE 0.08838834764831845f  // 1/sqrt(128)

typedef __attribute__((ext_vector_type(8))) short  short8;
typedef __attribute__((ext_vector_type(4))) float  floatx4;
typedef __attribute__((ext_vector_type(4))) unsigned int   uintx4;
typedef __attribute__((ext_vector_type(4))) unsigned short ushortx4;

__device__ __forceinline__ uint16_t f32_to_bf16(float x) {
    union { float f; uint32_t u; } v; v.f = x;
    return (uint16_t)((v.u + 0x7FFFu + ((v.u >> 16) & 1u)) >> 16);
}

// ---------------------------------------------------------------- zero dsum
__global__ void k_zero(float* __restrict__ p) {
    int i = blockIdx.x * 256 + threadIdx.x;
    if (i < N_ * M_) p[i] = 0.f;
}

// ---------------------------------------------------------------- q_val copy (channels 0..511)
__global__ __launch_bounds__(256) void k_copy_qval(const float* __restrict__ qv,
                                                   float* __restrict__ out) {
    unsigned i = blockIdx.x * 256 + threadIdx.x;     // one float4 each, 921600 total
    unsigned e = i * 4u;                              // < 3,686,400
    unsigned n = e / (CV * HW);
    unsigned off = e - n * (CV * HW);
    *(floatx4*)&out[(size_t)n * (2 * CV * HW) + off] = *(const floatx4*)&qv[e];
}

// ---------------------------------------------------------------- K1: aff = qk^T mk, exp, colsum
// A tile: ldsA[q][c] from q_key[n][c][q];  B tile: ldsB[m][c] from m_key[n][c][m]
#define K1_LDK 136   // 128 + 8 pad (shorts)

__global__ __launch_bounds__(256) void k1_gemm_exp(
    const float* __restrict__ qkey,   // [N][CK][HW]
    const float* __restrict__ mkey,   // [N][CK][M]
    uint16_t* __restrict__ E,         // [N][HW][M] bf16 = exp(aff*scale)
    float* __restrict__ dsum)         // [N][M]
{
    __shared__ short ldsA[128 * K1_LDK];
    __shared__ short ldsB[128 * K1_LDK];
    __shared__ float colsum[128];

    const int m0 = blockIdx.x * 128;
    const int q0 = blockIdx.y * 128;
    const int n  = blockIdx.z;
    const int tid = threadIdx.x;

    if (tid < 128) colsum[tid] = 0.f;

    {   // stage A (transpose): float4 along q
        const float* src = qkey + (size_t)n * CK * HW;
        for (int i4 = tid; i4 < 4096; i4 += 256) {
            int c  = i4 >> 5;
            int q4 = (i4 & 31) << 2;
            floatx4 v = {0.f, 0.f, 0.f, 0.f};
            if (q0 + q4 < HW) v = *(const floatx4*)&src[c * HW + q0 + q4];  // HW%4==0, 16B aligned
            ldsA[(q4 + 0) * K1_LDK + c] = (short)f32_to_bf16(v[0]);
            ldsA[(q4 + 1) * K1_LDK + c] = (short)f32_to_bf16(v[1]);
            ldsA[(q4 + 2) * K1_LDK + c] = (short)f32_to_bf16(v[2]);
            ldsA[(q4 + 3) * K1_LDK + c] = (short)f32_to_bf16(v[3]);
        }
    }
    {   // stage B (transpose): float4 along m
        const float* src = mkey + (size_t)n * CK * M_;
        for (int i4 = tid; i4 < 4096; i4 += 256) {
            int c  = i4 >> 5;
            int m4 = (i4 & 31) << 2;
            floatx4 v = {0.f, 0.f, 0.f, 0.f};
            if (m0 + m4 < M_) v = *(const floatx4*)&src[c * M_ + m0 + m4];
            ldsB[(m4 + 0) * K1_LDK + c] = (short)f32_to_bf16(v[0]);
            ldsB[(m4 + 1) * K1_LDK + c] = (short)f32_to_bf16(v[1]);
            ldsB[(m4 + 2) * K1_LDK + c] = (short)f32_to_bf16(v[2]);
            ldsB[(m4 + 3) * K1_LDK + c] = (short)f32_to_bf16(v[3]);
        }
    }
    __syncthreads();

    const int lane = tid & 63;
    const int wid  = tid >> 6;
    const int wq   = (wid >> 1) << 6;   // wave q base (0/64)
    const int wm   = (wid & 1) << 6;    // wave m base (0/64)
    const int fr   = lane & 15;
    const int quad = lane >> 4;

    floatx4 acc[4][4];
#pragma unroll
    for (int a = 0; a < 4; a++)
#pragma unroll
        for (int b = 0; b < 4; b++) acc[a][b] = (floatx4){0.f, 0.f, 0.f, 0.f};

#pragma unroll
    for (int ks = 0; ks < 4; ks++) {
        const int k0 = ks * 32 + quad * 8;
        short8 af[4], bfr[4];
#pragma unroll
        for (int t = 0; t < 4; t++)
            af[t] = *(const short8*)&ldsA[(wq + t * 16 + fr) * K1_LDK + k0];
#pragma unroll
        for (int t = 0; t < 4; t++)
            bfr[t] = *(const short8*)&ldsB[(wm + t * 16 + fr) * K1_LDK + k0];
#pragma unroll
        for (int tq = 0; tq < 4; tq++)
#pragma unroll
            for (int tm = 0; tm < 4; tm++)
                acc[tq][tm] = __builtin_amdgcn_mfma_f32_16x16x32_bf16(
                    af[tq], bfr[tm], acc[tq][tm], 0, 0, 0);
    }

    // epilogue: exp, store E, accumulate column sums (softmax is over q!)
    uint16_t* En = E + (size_t)n * HW * M_;
    float cs[4] = {0.f, 0.f, 0.f, 0.f};
#pragma unroll
    for (int tq = 0; tq < 4; tq++) {
#pragma unroll
        for (int tm = 0; tm < 4; tm++) {
            const int gm = m0 + wm + tm * 16 + fr;
#pragma unroll
            for (int i = 0; i < 4; i++) {
                const int gq = q0 + wq + tq * 16 + quad * 4 + i;
                if (gq < HW) {
                    float e = __expf(acc[tq][tm][i] * QK_SCALE);
                    cs[tm] += e;
                    if (gm < M_) En[(size_t)gq * M_ + gm] = f32_to_bf16(e);
                }
            }
        }
    }
#pragma unroll
    for (int tm = 0; tm < 4; tm++) {
        float s = cs[tm];
        s += __shfl_xor(s, 16, 64);   // reduce across quads (rows)
        s += __shfl_xor(s, 32, 64);
        if (quad == 0) atomicAdd(&colsum[wm + tm * 16 + fr], s);
    }
    __syncthreads();
    if (tid < 128) {
        const int gm = m0 + tid;
        if (gm < M_) atomicAdd(&dsum[(size_t)n * M_ + gm], colsum[tid]);
    }
}

// ---------------------------------------------------------------- dinv = 1/d
__global__ void k_dinv(const float* __restrict__ d, float* __restrict__ di) {
    int i = blockIdx.x * 256 + threadIdx.x;
    if (i < N_ * M_) di[i] = 1.0f / d[i];
}

// ---------------------------------------------------------------- mvs = bf16(mv * dinv[m])
__global__ __launch_bounds__(256) void k_mvs(
    const float* __restrict__ mval,   // [N][CV][M]
    const float* __restrict__ dinv,   // [N][M]
    uint16_t* __restrict__ mvs)       // [N][CV][M]
{
    unsigned i = blockIdx.x * 256 + threadIdx.x;   // one float4 each
    unsigned base = i * 4u;                         // < 29,491,200
    unsigned n = base / (unsigned)(CV * M_);
    unsigned m = base % (unsigned)M_;               // M_%4==0: never crosses a row
    floatx4 v  = *(const floatx4*)&mval[base];
    floatx4 di = *(const floatx4*)&dinv[n * (unsigned)M_ + m];
    ushortx4 o;
    o[0] = f32_to_bf16(v[0] * di[0]);
    o[1] = f32_to_bf16(v[1] * di[1]);
    o[2] = f32_to_bf16(v[2] * di[2]);
    o[3] = f32_to_bf16(v[3] * di[3]);
    *(ushortx4*)&mvs[base] = o;
}

// ---------------------------------------------------------------- K2: out[c][q] = sum_m mvs[c][m]*E[q][m]
#define K2_LD 104     // 96 + 8 pad (shorts)

__global__ __launch_bounds__(256) void k2_gemm_out(
    const uint16_t* __restrict__ mvs,  // [N][CV][M] bf16  (A: rows c, k=m)
    const uint16_t* __restrict__ E,    // [N][HW][M] bf16  (B: cols q, k=m)
    float* __restrict__ out)           // [N][1024][HW], mapped at ch 512..1023
{
    __shared__ short ldsA[128 * K2_LD];
    __shared__ short ldsB[128 * K2_LD];

    const int q0 = blockIdx.x * 128;
    const int c0 = blockIdx.y * 128;
    const int n  = blockIdx.z;
    const int tid = threadIdx.x;

    const int lane = tid & 63;
    const int wid  = tid >> 6;
    const int wc   = (wid >> 1) << 6;
    const int wq   = (wid & 1) << 6;
    const int fr   = lane & 15;
    const int quad = lane >> 4;

    floatx4 acc[4][4];
#pragma unroll
    for (int a = 0; a < 4; a++)
#pragma unroll
        for (int b = 0; b < 4; b++) acc[a][b] = (floatx4){0.f, 0.f, 0.f, 0.f};

    const uint16_t* Asrc = mvs + (size_t)(n * CV + c0) * M_;
    const uint16_t* Bsrc = E + (size_t)n * HW * M_;

    for (int step = 0; step < 75; step++) {
        const int m0 = step * 96;
        __syncthreads();
        // stage A: 128x96 bf16 = 1536 uint4 (8 bf16 each); contiguous, no transpose
#pragma unroll
        for (int j = 0; j < 6; j++) {
            int idx = tid + j * 256;
            int r   = idx / 12;
            int c8  = idx - r * 12;
            uintx4 v = *(const uintx4*)&Asrc[(size_t)r * M_ + m0 + c8 * 8];
            *(uintx4*)&ldsA[r * K2_LD + c8 * 8] = v;
        }
        // stage B (E rows, guard q >= 900 with zeros)
#pragma unroll
        for (int j = 0; j < 6; j++) {
            int idx = tid + j * 256;
            int r   = idx / 12;
            int c8  = idx - r * 12;
            uintx4 v = {0u, 0u, 0u, 0u};
            if (q0 + r < HW) v = *(const uintx4*)&Bsrc[(size_t)(q0 + r) * M_ + m0 + c8 * 8];
            *(uintx4*)&ldsB[r * K2_LD + c8 * 8] = v;
        }
        __syncthreads();
#pragma unroll
        for (int ks = 0; ks < 3; ks++) {
            const int k0 = ks * 32 + quad * 8;
            short8 af[4], bfr[4];
#pragma unroll
            for (int t = 0; t < 4; t++)
                af[t] = *(const short8*)&ldsA[(wc + t * 16 + fr) * K2_LD + k0];
#pragma unroll
            for (int t = 0; t < 4; t++)
                bfr[t] = *(const short8*)&ldsB[(wq + t * 16 + fr) * K2_LD + k0];
#pragma unroll
            for (int tc = 0; tc < 4; tc++)
#pragma unroll
                for (int tq = 0; tq < 4; tq++)
                    acc[tc][tq] = __builtin_amdgcn_mfma_f32_16x16x32_bf16(
                        af[tc], bfr[tq], acc[tc][tq], 0, 0, 0);
        }
    }

    // epilogue: D[row=c][col=q]; q contiguous across lanes -> coalesced
#pragma unroll
    for (int tc = 0; tc < 4; tc++) {
#pragma unroll
        for (int tq = 0; tq < 4; tq++) {
            const int gq = q0 + wq + tq * 16 + fr;
            if (gq < HW) {
#pragma unroll
                for (int i = 0; i < 4; i++) {
                    const int gc = c0 + wc + tc * 16 + quad * 4 + i;
                    out[((size_t)n * 1024 + 512 + gc) * HW + gq] = acc[tc][tq][i];
                }
            }
        }
    }
}

// ----------------------------------------------------------------
extern "C" void kernel_launch(void* const* d_in, const int* in_sizes, int n_in,
                              void* d_out, int out_size, void* d_ws, size_t ws_size,
                              hipStream_t stream) {
    const float* qkey = (const float*)d_in[0];  // [8][128][900]
    const float* qval = (const float*)d_in[1];  // [8][512][900]
    const float* mkey = (const float*)d_in[2];  // [8][128][7200]
    const float* mval = (const float*)d_in[3];  // [8][512][7200]
    float* out = (float*)d_out;                 // [8][1024][900]

    char* ws = (char*)d_ws;
    // layout: E 103,680,000 | dsum 230,400 | dinv 230,400 | mvs 58,982,400  (total 163.1 MB)
    uint16_t* E    = (uint16_t*)ws;
    float*    dsum = (float*)(ws + 103680000);
    float*    dinv = (float*)(ws + 103910400);
    uint16_t* mvs  = (uint16_t*)(ws + 104140800);

    (void)in_sizes; (void)n_in; (void)out_size; (void)ws_size;

    k_zero<<<dim3((N_ * M_ + 255) / 256), 256, 0, stream>>>(dsum);
    k_copy_qval<<<dim3((N_ * CV * HW) / 4 / 256), 256, 0, stream>>>(qval, out);
    k1_gemm_exp<<<dim3(57, 8, N_), 256, 0, stream>>>(qkey, mkey, E, dsum);
    k_dinv<<<dim3((N_ * M_ + 255) / 256), 256, 0, stream>>>(dsum, dinv);
    k_mvs<<<dim3((N_ * CV * M_) / 4 / 256), 256, 0, stream>>>(mval, dinv, mvs);
    k2_gemm_out<<<dim3(8, 4, N_), 256, 0, stream>>>(mvs, E, out);
}

// Round 4
// 538.824 us; speedup vs baseline: 1.2973x; 1.2973x over previous
//
#include <hip/hip_runtime.h>
#include <stdint.h>

#define N_  8
#define CK  128
#define CV  512
#define HW  900     // 30*30 queries
#define M_  7200    // 8*30*30 memory slots
#define QK_SCALE 0.08838834764831845f  // 1/sqrt(128)

typedef __attribute__((ext_vector_type(8))) short  short8;
typedef __attribute__((ext_vector_type(4))) float  floatx4;
typedef __attribute__((ext_vector_type(4))) unsigned int   uintx4;
typedef __attribute__((ext_vector_type(4))) unsigned short ushortx4;

__device__ __forceinline__ uint16_t f32_to_bf16(float x) {
    union { float f; uint32_t u; } v; v.f = x;
    return (uint16_t)((v.u + 0x7FFFu + ((v.u >> 16) & 1u)) >> 16);
}

// ---------------------------------------------------------------- zero dsum
__global__ void k_zero(float* __restrict__ p) {
    int i = blockIdx.x * 256 + threadIdx.x;
    if (i < N_ * M_) p[i] = 0.f;
}

// ---------------------------------------------------------------- q_val copy (channels 0..511)
__global__ __launch_bounds__(256) void k_copy_qval(const float* __restrict__ qv,
                                                   float* __restrict__ out) {
    unsigned i = blockIdx.x * 256 + threadIdx.x;
    unsigned e = i * 4u;
    unsigned n = e / (CV * HW);
    unsigned off = e - n * (CV * HW);
    *(floatx4*)&out[(size_t)n * (2 * CV * HW) + off] = *(const floatx4*)&qv[e];
}

// ---------------------------------------------------------------- K1: aff = qk^T mk, exp, colsum (round-1 verbatim, passing)
#define K1_LDK 136   // 128 + 8 pad (shorts)

__global__ __launch_bounds__(256) void k1_gemm_exp(
    const float* __restrict__ qkey,   // [N][CK][HW]
    const float* __restrict__ mkey,   // [N][CK][M]
    uint16_t* __restrict__ E,         // [N][HW][M] bf16 = exp(aff*scale)
    float* __restrict__ dsum)         // [N][M]
{
    __shared__ short ldsA[128 * K1_LDK];
    __shared__ short ldsB[128 * K1_LDK];
    __shared__ float colsum[128];

    const int m0 = blockIdx.x * 128;
    const int q0 = blockIdx.y * 128;
    const int n  = blockIdx.z;
    const int tid = threadIdx.x;

    if (tid < 128) colsum[tid] = 0.f;

    {   // stage A (transpose): float4 along q
        const float* src = qkey + (size_t)n * CK * HW;
        for (int i4 = tid; i4 < 4096; i4 += 256) {
            int c  = i4 >> 5;
            int q4 = (i4 & 31) << 2;
            floatx4 v = {0.f, 0.f, 0.f, 0.f};
            if (q0 + q4 < HW) v = *(const floatx4*)&src[c * HW + q0 + q4];
            ldsA[(q4 + 0) * K1_LDK + c] = (short)f32_to_bf16(v[0]);
            ldsA[(q4 + 1) * K1_LDK + c] = (short)f32_to_bf16(v[1]);
            ldsA[(q4 + 2) * K1_LDK + c] = (short)f32_to_bf16(v[2]);
            ldsA[(q4 + 3) * K1_LDK + c] = (short)f32_to_bf16(v[3]);
        }
    }
    {   // stage B (transpose): float4 along m
        const float* src = mkey + (size_t)n * CK * M_;
        for (int i4 = tid; i4 < 4096; i4 += 256) {
            int c  = i4 >> 5;
            int m4 = (i4 & 31) << 2;
            floatx4 v = {0.f, 0.f, 0.f, 0.f};
            if (m0 + m4 < M_) v = *(const floatx4*)&src[c * M_ + m0 + m4];
            ldsB[(m4 + 0) * K1_LDK + c] = (short)f32_to_bf16(v[0]);
            ldsB[(m4 + 1) * K1_LDK + c] = (short)f32_to_bf16(v[1]);
            ldsB[(m4 + 2) * K1_LDK + c] = (short)f32_to_bf16(v[2]);
            ldsB[(m4 + 3) * K1_LDK + c] = (short)f32_to_bf16(v[3]);
        }
    }
    __syncthreads();

    const int lane = tid & 63;
    const int wid  = tid >> 6;
    const int wq   = (wid >> 1) << 6;
    const int wm   = (wid & 1) << 6;
    const int fr   = lane & 15;
    const int quad = lane >> 4;

    floatx4 acc[4][4];
#pragma unroll
    for (int a = 0; a < 4; a++)
#pragma unroll
        for (int b = 0; b < 4; b++) acc[a][b] = (floatx4){0.f, 0.f, 0.f, 0.f};

#pragma unroll
    for (int ks = 0; ks < 4; ks++) {
        const int k0 = ks * 32 + quad * 8;
        short8 af[4], bfr[4];
#pragma unroll
        for (int t = 0; t < 4; t++)
            af[t] = *(const short8*)&ldsA[(wq + t * 16 + fr) * K1_LDK + k0];
#pragma unroll
        for (int t = 0; t < 4; t++)
            bfr[t] = *(const short8*)&ldsB[(wm + t * 16 + fr) * K1_LDK + k0];
#pragma unroll
        for (int tq = 0; tq < 4; tq++)
#pragma unroll
            for (int tm = 0; tm < 4; tm++)
                acc[tq][tm] = __builtin_amdgcn_mfma_f32_16x16x32_bf16(
                    af[tq], bfr[tm], acc[tq][tm], 0, 0, 0);
    }

    uint16_t* En = E + (size_t)n * HW * M_;
    float cs[4] = {0.f, 0.f, 0.f, 0.f};
#pragma unroll
    for (int tq = 0; tq < 4; tq++) {
#pragma unroll
        for (int tm = 0; tm < 4; tm++) {
            const int gm = m0 + wm + tm * 16 + fr;
#pragma unroll
            for (int i = 0; i < 4; i++) {
                const int gq = q0 + wq + tq * 16 + quad * 4 + i;
                if (gq < HW) {
                    float e = __expf(acc[tq][tm][i] * QK_SCALE);
                    cs[tm] += e;
                    if (gm < M_) En[(size_t)gq * M_ + gm] = f32_to_bf16(e);
                }
            }
        }
    }
#pragma unroll
    for (int tm = 0; tm < 4; tm++) {
        float s = cs[tm];
        s += __shfl_xor(s, 16, 64);
        s += __shfl_xor(s, 32, 64);
        if (quad == 0) atomicAdd(&colsum[wm + tm * 16 + fr], s);
    }
    __syncthreads();
    if (tid < 128) {
        const int gm = m0 + tid;
        if (gm < M_) atomicAdd(&dsum[(size_t)n * M_ + gm], colsum[tid]);
    }
}

// ---------------------------------------------------------------- dinv = 1/d
__global__ void k_dinv(const float* __restrict__ d, float* __restrict__ di) {
    int i = blockIdx.x * 256 + threadIdx.x;
    if (i < N_ * M_) di[i] = 1.0f / d[i];
}

// ---------------------------------------------------------------- mvs = bf16(mv * dinv[m])
__global__ __launch_bounds__(256) void k_mvs(
    const float* __restrict__ mval,   // [N][CV][M]
    const float* __restrict__ dinv,   // [N][M]
    uint16_t* __restrict__ mvs)       // [N][CV][M]
{
    unsigned i = blockIdx.x * 256 + threadIdx.x;
    unsigned base = i * 4u;
    unsigned n = base / (unsigned)(CV * M_);
    unsigned m = base % (unsigned)M_;
    floatx4 v  = *(const floatx4*)&mval[base];
    floatx4 di = *(const floatx4*)&dinv[n * (unsigned)M_ + m];
    ushortx4 o;
    o[0] = f32_to_bf16(v[0] * di[0]);
    o[1] = f32_to_bf16(v[1] * di[1]);
    o[2] = f32_to_bf16(v[2] * di[2]);
    o[3] = f32_to_bf16(v[3] * di[3]);
    *(ushortx4*)&mvs[base] = o;
}

// ---------------------------------------------------------------- K2 split x3: round-1 inner loop VERBATIM
// (single-buffered, no launch_bounds min-wave promise, no register prefetch).
// Only deltas vs the passing round-1 kernel: base += split*2400, 25 steps, store to partials.
// Occupancy: grid 768 blocks = 3/CU; LDS 3x53,248 = 159,744 <= 163,840 -> 3 resident.
#define K2_LD 104     // 96 + 8 pad (shorts)
#define K2_SPLITS 3
#define K2_STEPS 25   // 2400 / 96

__global__ __launch_bounds__(256) void k2_split3(
    const uint16_t* __restrict__ mvs,  // [N][CV][M] bf16
    const uint16_t* __restrict__ E,    // [N][HW][M] bf16
    float* __restrict__ partials)      // [3][N][CV][HW]
{
    __shared__ short ldsA[128 * K2_LD];
    __shared__ short ldsB[128 * K2_LD];

    const int q0 = blockIdx.x * 128;
    const int c0 = blockIdx.y * 128;
    const int nz = blockIdx.z;
    const int n     = nz / K2_SPLITS;
    const int split = nz - n * K2_SPLITS;
    const int tid = threadIdx.x;

    const int lane = tid & 63;
    const int wid  = tid >> 6;
    const int wc   = (wid >> 1) << 6;
    const int wq   = (wid & 1) << 6;
    const int fr   = lane & 15;
    const int quad = lane >> 4;

    floatx4 acc[4][4];
#pragma unroll
    for (int a = 0; a < 4; a++)
#pragma unroll
        for (int b = 0; b < 4; b++) acc[a][b] = (floatx4){0.f, 0.f, 0.f, 0.f};

    const uint16_t* Asrc = mvs + (size_t)(n * CV + c0) * M_ + split * 2400;
    const uint16_t* Bsrc = E + (size_t)n * HW * M_ + split * 2400;

    for (int step = 0; step < K2_STEPS; step++) {
        const int m0 = step * 96;
        __syncthreads();
#pragma unroll
        for (int j = 0; j < 6; j++) {
            int idx = tid + j * 256;
            int r   = idx / 12;
            int c8  = idx - r * 12;
            uintx4 v = *(const uintx4*)&Asrc[(size_t)r * M_ + m0 + c8 * 8];
            *(uintx4*)&ldsA[r * K2_LD + c8 * 8] = v;
        }
#pragma unroll
        for (int j = 0; j < 6; j++) {
            int idx = tid + j * 256;
            int r   = idx / 12;
            int c8  = idx - r * 12;
            uintx4 v = {0u, 0u, 0u, 0u};
            if (q0 + r < HW) v = *(const uintx4*)&Bsrc[(size_t)(q0 + r) * M_ + m0 + c8 * 8];
            *(uintx4*)&ldsB[r * K2_LD + c8 * 8] = v;
        }
        __syncthreads();
#pragma unroll
        for (int ks = 0; ks < 3; ks++) {
            const int k0 = ks * 32 + quad * 8;
            short8 af[4], bfr[4];
#pragma unroll
            for (int t = 0; t < 4; t++)
                af[t] = *(const short8*)&ldsA[(wc + t * 16 + fr) * K2_LD + k0];
#pragma unroll
            for (int t = 0; t < 4; t++)
                bfr[t] = *(const short8*)&ldsB[(wq + t * 16 + fr) * K2_LD + k0];
#pragma unroll
            for (int tc = 0; tc < 4; tc++)
#pragma unroll
                for (int tq = 0; tq < 4; tq++)
                    acc[tc][tq] = __builtin_amdgcn_mfma_f32_16x16x32_bf16(
                        af[tc], bfr[tq], acc[tc][tq], 0, 0, 0);
        }
    }

    // plain stores; each (split, c, q) owned by exactly one block
    float* P = partials + ((size_t)split * N_ + n) * CV * HW;
#pragma unroll
    for (int tc = 0; tc < 4; tc++) {
#pragma unroll
        for (int tq = 0; tq < 4; tq++) {
            const int gq = q0 + wq + tq * 16 + fr;
            if (gq < HW) {
#pragma unroll
                for (int i = 0; i < 4; i++) {
                    const int gc = c0 + wc + tc * 16 + quad * 4 + i;
                    P[(size_t)gc * HW + gq] = acc[tc][tq][i];
                }
            }
        }
    }
}

// ---------------------------------------------------------------- reduce 3 partials -> out mapped half
__global__ __launch_bounds__(256) void k_reduce3(const float* __restrict__ partials,
                                                 float* __restrict__ out) {
    unsigned i = blockIdx.x * 256 + threadIdx.x;
    unsigned e = i * 4u;                          // < 3,686,400 = N*CV*HW
    unsigned n = e / (CV * HW);
    unsigned off = e - n * (CV * HW);
    const size_t stride = (size_t)N_ * CV * HW;
    const float* p = partials + (size_t)n * CV * HW + off;
    floatx4 a = *(const floatx4*)&p[0];
    floatx4 b = *(const floatx4*)&p[stride];
    floatx4 c = *(const floatx4*)&p[2 * stride];
    floatx4 s = a + b + c;
    *(floatx4*)&out[(size_t)n * (2 * CV * HW) + CV * HW + off] = s;
}

// ---------------------------------------------------------------- K2 monolithic fallback (round-1 verbatim, passing)
__global__ __launch_bounds__(256) void k2_mono(
    const uint16_t* __restrict__ mvs,
    const uint16_t* __restrict__ E,
    float* __restrict__ out)
{
    __shared__ short ldsA[128 * K2_LD];
    __shared__ short ldsB[128 * K2_LD];

    const int q0 = blockIdx.x * 128;
    const int c0 = blockIdx.y * 128;
    const int n  = blockIdx.z;
    const int tid = threadIdx.x;

    const int lane = tid & 63;
    const int wid  = tid >> 6;
    const int wc   = (wid >> 1) << 6;
    const int wq   = (wid & 1) << 6;
    const int fr   = lane & 15;
    const int quad = lane >> 4;

    floatx4 acc[4][4];
#pragma unroll
    for (int a = 0; a < 4; a++)
#pragma unroll
        for (int b = 0; b < 4; b++) acc[a][b] = (floatx4){0.f, 0.f, 0.f, 0.f};

    const uint16_t* Asrc = mvs + (size_t)(n * CV + c0) * M_;
    const uint16_t* Bsrc = E + (size_t)n * HW * M_;

    for (int step = 0; step < 75; step++) {
        const int m0 = step * 96;
        __syncthreads();
#pragma unroll
        for (int j = 0; j < 6; j++) {
            int idx = tid + j * 256;
            int r   = idx / 12;
            int c8  = idx - r * 12;
            uintx4 v = *(const uintx4*)&Asrc[(size_t)r * M_ + m0 + c8 * 8];
            *(uintx4*)&ldsA[r * K2_LD + c8 * 8] = v;
        }
#pragma unroll
        for (int j = 0; j < 6; j++) {
            int idx = tid + j * 256;
            int r   = idx / 12;
            int c8  = idx - r * 12;
            uintx4 v = {0u, 0u, 0u, 0u};
            if (q0 + r < HW) v = *(const uintx4*)&Bsrc[(size_t)(q0 + r) * M_ + m0 + c8 * 8];
            *(uintx4*)&ldsB[r * K2_LD + c8 * 8] = v;
        }
        __syncthreads();
#pragma unroll
        for (int ks = 0; ks < 3; ks++) {
            const int k0 = ks * 32 + quad * 8;
            short8 af[4], bfr[4];
#pragma unroll
            for (int t = 0; t < 4; t++)
                af[t] = *(const short8*)&ldsA[(wc + t * 16 + fr) * K2_LD + k0];
#pragma unroll
            for (int t = 0; t < 4; t++)
                bfr[t] = *(const short8*)&ldsB[(wq + t * 16 + fr) * K2_LD + k0];
#pragma unroll
            for (int tc = 0; tc < 4; tc++)
#pragma unroll
                for (int tq = 0; tq < 4; tq++)
                    acc[tc][tq] = __builtin_amdgcn_mfma_f32_16x16x32_bf16(
                        af[tc], bfr[tq], acc[tc][tq], 0, 0, 0);
        }
    }

#pragma unroll
    for (int tc = 0; tc < 4; tc++) {
#pragma unroll
        for (int tq = 0; tq < 4; tq++) {
            const int gq = q0 + wq + tq * 16 + fr;
            if (gq < HW) {
#pragma unroll
                for (int i = 0; i < 4; i++) {
                    const int gc = c0 + wc + tc * 16 + quad * 4 + i;
                    out[((size_t)n * 1024 + 512 + gc) * HW + gq] = acc[tc][tq][i];
                }
            }
        }
    }
}

// ----------------------------------------------------------------
extern "C" void kernel_launch(void* const* d_in, const int* in_sizes, int n_in,
                              void* d_out, int out_size, void* d_ws, size_t ws_size,
                              hipStream_t stream) {
    const float* qkey = (const float*)d_in[0];
    const float* qval = (const float*)d_in[1];
    const float* mkey = (const float*)d_in[2];
    const float* mval = (const float*)d_in[3];
    float* out = (float*)d_out;

    char* ws = (char*)d_ws;
    // E 103,680,000 | dsum 230,400 | dinv 230,400 | mvs 58,982,400 | partials 44,236,800 = 207,360,000
    uint16_t* E        = (uint16_t*)ws;
    float*    dsum     = (float*)(ws + 103680000);
    float*    dinv     = (float*)(ws + 103910400);
    uint16_t* mvs      = (uint16_t*)(ws + 104140800);
    float*    partials = (float*)(ws + 163123200);

    (void)in_sizes; (void)n_in; (void)out_size;

    k_zero<<<dim3((N_ * M_ + 255) / 256), 256, 0, stream>>>(dsum);
    k_copy_qval<<<dim3((N_ * CV * HW) / 4 / 256), 256, 0, stream>>>(qval, out);
    k1_gemm_exp<<<dim3(57, 8, N_), 256, 0, stream>>>(qkey, mkey, E, dsum);
    k_dinv<<<dim3((N_ * M_ + 255) / 256), 256, 0, stream>>>(dsum, dinv);
    k_mvs<<<dim3((N_ * CV * M_) / 4 / 256), 256, 0, stream>>>(mval, dinv, mvs);

    if (ws_size >= (size_t)207360000) {
        k2_split3<<<dim3(8, 4, N_ * K2_SPLITS), 256, 0, stream>>>(mvs, E, partials);
        k_reduce3<<<dim3((N_ * CV * HW) / 4 / 256), 256, 0, stream>>>(partials, out);
    } else {
        k2_mono<<<dim3(8, 4, N_), 256, 0, stream>>>(mvs, E, out);
    }
}

// Round 5
// 462.327 us; speedup vs baseline: 1.5119x; 1.1655x over previous
//
#include <hip/hip_runtime.h>
#include <stdint.h>

#define N_  8
#define CK  128
#define CV  512
#define HW  900     // 30*30 queries
#define M_  7200    // 8*30*30 memory slots
#define QK_SCALE 0.08838834764831845f  // 1/sqrt(128)

typedef __attribute__((ext_vector_type(8))) short  short8;
typedef __attribute__((ext_vector_type(4))) float  floatx4;
typedef __attribute__((ext_vector_type(4))) unsigned int   uintx4;
typedef __attribute__((ext_vector_type(4))) unsigned short ushortx4;

__device__ __forceinline__ uint16_t f32_to_bf16(float x) {
    union { float f; uint32_t u; } v; v.f = x;
    return (uint16_t)((v.u + 0x7FFFu + ((v.u >> 16) & 1u)) >> 16);
}

// ---------------------------------------------------------------- zero dsum
__global__ void k_zero(float* __restrict__ p) {
    int i = blockIdx.x * 256 + threadIdx.x;
    if (i < N_ * M_) p[i] = 0.f;
}

// ---------------------------------------------------------------- q_val copy (channels 0..511)
__global__ __launch_bounds__(256) void k_copy_qval(const float* __restrict__ qv,
                                                   float* __restrict__ out) {
    unsigned i = blockIdx.x * 256 + threadIdx.x;
    unsigned e = i * 4u;
    unsigned n = e / (CV * HW);
    unsigned off = e - n * (CV * HW);
    *(floatx4*)&out[(size_t)n * (2 * CV * HW) + off] = *(const floatx4*)&qv[e];
}

// ---------------------------------------------------------------- transpose [N][CK][L] fp32 -> [N][L][CK] bf16
__global__ __launch_bounds__(256) void k_trans(const float* __restrict__ in,
                                               uint16_t* __restrict__ outp, int L) {
    __shared__ float tile[32][33];
    const int tx = threadIdx.x & 31;
    const int ty = threadIdx.x >> 5;      // 0..7
    const int l0 = blockIdx.x * 32;
    const int c0 = blockIdx.y * 32;
    const int n  = blockIdx.z;
    const float* src = in + (size_t)n * CK * L;
    uint16_t* dst = outp + (size_t)n * L * CK;
#pragma unroll
    for (int p = 0; p < 4; p++) {
        int c = c0 + p * 8 + ty;          // CK=128, grid.y=4: no c guard needed
        int l = l0 + tx;
        float v = 0.f;
        if (l < L) v = src[(size_t)c * L + l];
        tile[p * 8 + ty][tx] = v;
    }
    __syncthreads();
#pragma unroll
    for (int p = 0; p < 4; p++) {
        int l = l0 + p * 8 + ty;
        int c = c0 + tx;
        if (l < L) dst[(size_t)l * CK + c] = f32_to_bf16(tile[tx][p * 8 + ty]);
    }
}

// ---------------------------------------------------------------- K1: aff = qkT mkT^T, exp, colsum
// Pre-transposed bf16 operands; k2-style uint4 staging (no in-kernel transpose).
#define K1_LD 72   // 64 + 8 pad (shorts)

__global__ __launch_bounds__(256) void k1_gemm_exp(
    const uint16_t* __restrict__ qkT,  // [N][HW][CK] bf16 (A: rows q, k=c)
    const uint16_t* __restrict__ mkT,  // [N][M][CK] bf16  (B: rows m, k=c)
    uint16_t* __restrict__ E,          // [N][HW][M] bf16 = exp(aff*scale)
    float* __restrict__ dsum)          // [N][M]
{
    __shared__ short ldsA[128 * K1_LD];
    __shared__ short ldsB[128 * K1_LD];
    __shared__ float colsum[128];

    const int m0 = blockIdx.x * 128;
    const int q0 = blockIdx.y * 128;
    const int n  = blockIdx.z;
    const int tid = threadIdx.x;

    if (tid < 128) colsum[tid] = 0.f;

    const int lane = tid & 63;
    const int wid  = tid >> 6;
    const int wq   = (wid >> 1) << 6;
    const int wm   = (wid & 1) << 6;
    const int fr   = lane & 15;
    const int quad = lane >> 4;

    floatx4 acc[4][4];
#pragma unroll
    for (int a = 0; a < 4; a++)
#pragma unroll
        for (int b = 0; b < 4; b++) acc[a][b] = (floatx4){0.f, 0.f, 0.f, 0.f};

    const uint16_t* Ab = qkT + (size_t)n * HW * CK;
    const uint16_t* Bb = mkT + (size_t)n * M_ * CK;

#pragma unroll
    for (int kc = 0; kc < 2; kc++) {
        __syncthreads();
        // stage A: 128 rows x 64 bf16 = 1024 uint4, 4/thread
#pragma unroll
        for (int j = 0; j < 4; j++) {
            int idx = tid + j * 256;
            int r   = idx >> 3;
            int c8  = (idx & 7) * 8;
            uintx4 v = {0u, 0u, 0u, 0u};
            if (q0 + r < HW) v = *(const uintx4*)&Ab[(size_t)(q0 + r) * CK + kc * 64 + c8];
            *(uintx4*)&ldsA[r * K1_LD + c8] = v;
        }
#pragma unroll
        for (int j = 0; j < 4; j++) {
            int idx = tid + j * 256;
            int r   = idx >> 3;
            int c8  = (idx & 7) * 8;
            uintx4 v = {0u, 0u, 0u, 0u};
            if (m0 + r < M_) v = *(const uintx4*)&Bb[(size_t)(m0 + r) * CK + kc * 64 + c8];
            *(uintx4*)&ldsB[r * K1_LD + c8] = v;
        }
        __syncthreads();
#pragma unroll
        for (int ks = 0; ks < 2; ks++) {
            const int k0 = ks * 32 + quad * 8;
            short8 af[4], bfr[4];
#pragma unroll
            for (int t = 0; t < 4; t++)
                af[t] = *(const short8*)&ldsA[(wq + t * 16 + fr) * K1_LD + k0];
#pragma unroll
            for (int t = 0; t < 4; t++)
                bfr[t] = *(const short8*)&ldsB[(wm + t * 16 + fr) * K1_LD + k0];
#pragma unroll
            for (int tq = 0; tq < 4; tq++)
#pragma unroll
                for (int tm = 0; tm < 4; tm++)
                    acc[tq][tm] = __builtin_amdgcn_mfma_f32_16x16x32_bf16(
                        af[tq], bfr[tm], acc[tq][tm], 0, 0, 0);
        }
    }

    uint16_t* En = E + (size_t)n * HW * M_;
    float cs[4] = {0.f, 0.f, 0.f, 0.f};
#pragma unroll
    for (int tq = 0; tq < 4; tq++) {
#pragma unroll
        for (int tm = 0; tm < 4; tm++) {
            const int gm = m0 + wm + tm * 16 + fr;
#pragma unroll
            for (int i = 0; i < 4; i++) {
                const int gq = q0 + wq + tq * 16 + quad * 4 + i;
                if (gq < HW) {
                    float e = __expf(acc[tq][tm][i] * QK_SCALE);
                    cs[tm] += e;
                    if (gm < M_) En[(size_t)gq * M_ + gm] = f32_to_bf16(e);
                }
            }
        }
    }
#pragma unroll
    for (int tm = 0; tm < 4; tm++) {
        float s = cs[tm];
        s += __shfl_xor(s, 16, 64);
        s += __shfl_xor(s, 32, 64);
        if (quad == 0) atomicAdd(&colsum[wm + tm * 16 + fr], s);
    }
    __syncthreads();
    if (tid < 128) {
        const int gm = m0 + tid;
        if (gm < M_) atomicAdd(&dsum[(size_t)n * M_ + gm], colsum[tid]);
    }
}

// ---------------------------------------------------------------- dinv = 1/d
__global__ void k_dinv(const float* __restrict__ d, float* __restrict__ di) {
    int i = blockIdx.x * 256 + threadIdx.x;
    if (i < N_ * M_) di[i] = 1.0f / d[i];
}

// ---------------------------------------------------------------- mvs = bf16(mv * dinv[m])
__global__ __launch_bounds__(256) void k_mvs(
    const float* __restrict__ mval,   // [N][CV][M]
    const float* __restrict__ dinv,   // [N][M]
    uint16_t* __restrict__ mvs)       // [N][CV][M]
{
    unsigned i = blockIdx.x * 256 + threadIdx.x;
    unsigned base = i * 4u;
    unsigned n = base / (unsigned)(CV * M_);
    unsigned m = base % (unsigned)M_;
    floatx4 v  = *(const floatx4*)&mval[base];
    floatx4 di = *(const floatx4*)&dinv[n * (unsigned)M_ + m];
    ushortx4 o;
    o[0] = f32_to_bf16(v[0] * di[0]);
    o[1] = f32_to_bf16(v[1] * di[1]);
    o[2] = f32_to_bf16(v[2] * di[2]);
    o[3] = f32_to_bf16(v[3] * di[3]);
    *(ushortx4*)&mvs[base] = o;
}

// ---------------------------------------------------------------- K2 split x3 (round-4 verbatim, passing)
#define K2_LD 104     // 96 + 8 pad (shorts)
#define K2_SPLITS 3
#define K2_STEPS 25   // 2400 / 96

__global__ __launch_bounds__(256) void k2_split3(
    const uint16_t* __restrict__ mvs,  // [N][CV][M] bf16
    const uint16_t* __restrict__ E,    // [N][HW][M] bf16
    float* __restrict__ partials)      // [3][N][CV][HW]
{
    __shared__ short ldsA[128 * K2_LD];
    __shared__ short ldsB[128 * K2_LD];

    const int q0 = blockIdx.x * 128;
    const int c0 = blockIdx.y * 128;
    const int nz = blockIdx.z;
    const int n     = nz / K2_SPLITS;
    const int split = nz - n * K2_SPLITS;
    const int tid = threadIdx.x;

    const int lane = tid & 63;
    const int wid  = tid >> 6;
    const int wc   = (wid >> 1) << 6;
    const int wq   = (wid & 1) << 6;
    const int fr   = lane & 15;
    const int quad = lane >> 4;

    floatx4 acc[4][4];
#pragma unroll
    for (int a = 0; a < 4; a++)
#pragma unroll
        for (int b = 0; b < 4; b++) acc[a][b] = (floatx4){0.f, 0.f, 0.f, 0.f};

    const uint16_t* Asrc = mvs + (size_t)(n * CV + c0) * M_ + split * 2400;
    const uint16_t* Bsrc = E + (size_t)n * HW * M_ + split * 2400;

    for (int step = 0; step < K2_STEPS; step++) {
        const int m0 = step * 96;
        __syncthreads();
#pragma unroll
        for (int j = 0; j < 6; j++) {
            int idx = tid + j * 256;
            int r   = idx / 12;
            int c8  = idx - r * 12;
            uintx4 v = *(const uintx4*)&Asrc[(size_t)r * M_ + m0 + c8 * 8];
            *(uintx4*)&ldsA[r * K2_LD + c8 * 8] = v;
        }
#pragma unroll
        for (int j = 0; j < 6; j++) {
            int idx = tid + j * 256;
            int r   = idx / 12;
            int c8  = idx - r * 12;
            uintx4 v = {0u, 0u, 0u, 0u};
            if (q0 + r < HW) v = *(const uintx4*)&Bsrc[(size_t)(q0 + r) * M_ + m0 + c8 * 8];
            *(uintx4*)&ldsB[r * K2_LD + c8 * 8] = v;
        }
        __syncthreads();
#pragma unroll
        for (int ks = 0; ks < 3; ks++) {
            const int k0 = ks * 32 + quad * 8;
            short8 af[4], bfr[4];
#pragma unroll
            for (int t = 0; t < 4; t++)
                af[t] = *(const short8*)&ldsA[(wc + t * 16 + fr) * K2_LD + k0];
#pragma unroll
            for (int t = 0; t < 4; t++)
                bfr[t] = *(const short8*)&ldsB[(wq + t * 16 + fr) * K2_LD + k0];
#pragma unroll
            for (int tc = 0; tc < 4; tc++)
#pragma unroll
                for (int tq = 0; tq < 4; tq++)
                    acc[tc][tq] = __builtin_amdgcn_mfma_f32_16x16x32_bf16(
                        af[tc], bfr[tq], acc[tc][tq], 0, 0, 0);
        }
    }

    float* P = partials + ((size_t)split * N_ + n) * CV * HW;
#pragma unroll
    for (int tc = 0; tc < 4; tc++) {
#pragma unroll
        for (int tq = 0; tq < 4; tq++) {
            const int gq = q0 + wq + tq * 16 + fr;
            if (gq < HW) {
#pragma unroll
                for (int i = 0; i < 4; i++) {
                    const int gc = c0 + wc + tc * 16 + quad * 4 + i;
                    P[(size_t)gc * HW + gq] = acc[tc][tq][i];
                }
            }
        }
    }
}

// ---------------------------------------------------------------- reduce 3 partials -> out mapped half
__global__ __launch_bounds__(256) void k_reduce3(const float* __restrict__ partials,
                                                 float* __restrict__ out) {
    unsigned i = blockIdx.x * 256 + threadIdx.x;
    unsigned e = i * 4u;                          // < 3,686,400 = N*CV*HW
    unsigned n = e / (CV * HW);
    unsigned off = e - n * (CV * HW);
    const size_t stride = (size_t)N_ * CV * HW;
    const float* p = partials + (size_t)n * CV * HW + off;
    floatx4 a = *(const floatx4*)&p[0];
    floatx4 b = *(const floatx4*)&p[stride];
    floatx4 c = *(const floatx4*)&p[2 * stride];
    floatx4 s = a + b + c;
    *(floatx4*)&out[(size_t)n * (2 * CV * HW) + CV * HW + off] = s;
}

// ----------------------------------------------------------------
extern "C" void kernel_launch(void* const* d_in, const int* in_sizes, int n_in,
                              void* d_out, int out_size, void* d_ws, size_t ws_size,
                              hipStream_t stream) {
    const float* qkey = (const float*)d_in[0];  // [8][128][900]
    const float* qval = (const float*)d_in[1];  // [8][512][900]
    const float* mkey = (const float*)d_in[2];  // [8][128][7200]
    const float* mval = (const float*)d_in[3];  // [8][512][7200]
    float* out = (float*)d_out;                 // [8][1024][900]

    char* ws = (char*)d_ws;
    // E 103,680,000 | dsum 230,400 | dinv 230,400 | mvs 58,982,400 | partials 44,236,800 = 207,360,000
    // qkT (1,843,200) + mkT (14,745,600) alias the partials region: they are dead
    // before k2_split3 (the only writer of partials) launches.
    uint16_t* E        = (uint16_t*)ws;
    float*    dsum     = (float*)(ws + 103680000);
    float*    dinv     = (float*)(ws + 103910400);
    uint16_t* mvs      = (uint16_t*)(ws + 104140800);
    float*    partials = (float*)(ws + 163123200);
    uint16_t* qkT      = (uint16_t*)(ws + 163123200);
    uint16_t* mkT      = (uint16_t*)(ws + 163123200 + 1843200);

    (void)in_sizes; (void)n_in; (void)out_size; (void)ws_size;

    k_zero<<<dim3((N_ * M_ + 255) / 256), 256, 0, stream>>>(dsum);
    k_copy_qval<<<dim3((N_ * CV * HW) / 4 / 256), 256, 0, stream>>>(qval, out);
    k_trans<<<dim3(29, 4, N_), 256, 0, stream>>>(qkey, qkT, HW);
    k_trans<<<dim3(225, 4, N_), 256, 0, stream>>>(mkey, mkT, M_);
    k1_gemm_exp<<<dim3(57, 8, N_), 256, 0, stream>>>(qkT, mkT, E, dsum);
    k_dinv<<<dim3((N_ * M_ + 255) / 256), 256, 0, stream>>>(dsum, dinv);
    k_mvs<<<dim3((N_ * CV * M_) / 4 / 256), 256, 0, stream>>>(mval, dinv, mvs);
    k2_split3<<<dim3(8, 4, N_ * K2_SPLITS), 256, 0, stream>>>(mvs, E, partials);
    k_reduce3<<<dim3((N_ * CV * HW) / 4 / 256), 256, 0, stream>>>(partials, out);
}

// Round 7
// 455.348 us; speedup vs baseline: 1.5351x; 1.0153x over previous
//
#include <hip/hip_runtime.h>
#include <stdint.h>

#define N_  8
#define CK  128
#define CV  512
#define HW  900     // 30*30 queries
#define M_  7200    // 8*30*30 memory slots
#define QK_SCALE 0.08838834764831845f  // 1/sqrt(128)

typedef __attribute__((ext_vector_type(8))) short  short8;
typedef __attribute__((ext_vector_type(4))) float  floatx4;
typedef __attribute__((ext_vector_type(4))) unsigned int   uintx4;
typedef __attribute__((ext_vector_type(4))) unsigned short ushortx4;

__device__ __forceinline__ uint16_t f32_to_bf16(float x) {
    union { float f; uint32_t u; } v; v.f = x;
    return (uint16_t)((v.u + 0x7FFFu + ((v.u >> 16) & 1u)) >> 16);
}

// ---------------------------------------------------------------- zero dsum
__global__ void k_zero(float* __restrict__ p) {
    int i = blockIdx.x * 256 + threadIdx.x;
    if (i < N_ * M_) p[i] = 0.f;
}

// ---------------------------------------------------------------- q_val copy (channels 0..511)
__global__ __launch_bounds__(256) void k_copy_qval(const float* __restrict__ qv,
                                                   float* __restrict__ out) {
    unsigned i = blockIdx.x * 256 + threadIdx.x;
    unsigned e = i * 4u;
    unsigned n = e / (CV * HW);
    unsigned off = e - n * (CV * HW);
    *(floatx4*)&out[(size_t)n * (2 * CV * HW) + off] = *(const floatx4*)&qv[e];
}

// ---------------------------------------------------------------- transpose [N][CK][L] fp32 -> [N][L][CK] bf16
__global__ __launch_bounds__(256) void k_trans(const float* __restrict__ in,
                                               uint16_t* __restrict__ outp, int L) {
    __shared__ float tile[32][33];
    const int tx = threadIdx.x & 31;
    const int ty = threadIdx.x >> 5;      // 0..7
    const int l0 = blockIdx.x * 32;
    const int c0 = blockIdx.y * 32;
    const int n  = blockIdx.z;
    const float* src = in + (size_t)n * CK * L;
    uint16_t* dst = outp + (size_t)n * L * CK;
#pragma unroll
    for (int p = 0; p < 4; p++) {
        int c = c0 + p * 8 + ty;
        int l = l0 + tx;
        float v = 0.f;
        if (l < L) v = src[(size_t)c * L + l];
        tile[p * 8 + ty][tx] = v;
    }
    __syncthreads();
#pragma unroll
    for (int p = 0; p < 4; p++) {
        int l = l0 + p * 8 + ty;
        int c = c0 + tx;
        if (l < L) dst[(size_t)l * CK + c] = f32_to_bf16(tile[tx][p * 8 + ty]);
    }
}

// ---------------------------------------------------------------- K1: aff = qkT mkT^T, exp, colsum
// Epilogue round-trips C through LDS for coalesced uint4 E-writes.
#define K1_LD 72    // 64 + 8 pad (shorts) — staging layout (proven round 5)
#define K1_TS 144   // transpose-tile stride (shorts): quads land on disjoint banks; rows 16B-aligned

__global__ __launch_bounds__(256) void k1_gemm_exp(
    const uint16_t* __restrict__ qkT,  // [N][HW][CK] bf16 (A: rows q, k=c)
    const uint16_t* __restrict__ mkT,  // [N][M][CK] bf16  (B: rows m, k=c)
    uint16_t* __restrict__ E,          // [N][HW][M] bf16 = exp(aff*scale)
    float* __restrict__ dsum)          // [N][M]
{
    __shared__ __align__(16) short smem[18432];  // ldsA(9216) + ldsB(9216); reused as 128x144 C-tile
    __shared__ float colsum[128];
    short* ldsA = smem;
    short* ldsB = smem + 9216;

    const int m0 = blockIdx.x * 128;
    const int q0 = blockIdx.y * 128;
    const int n  = blockIdx.z;
    const int tid = threadIdx.x;

    if (tid < 128) colsum[tid] = 0.f;

    const int lane = tid & 63;
    const int wid  = tid >> 6;
    const int wq   = (wid >> 1) << 6;
    const int wm   = (wid & 1) << 6;
    const int fr   = lane & 15;
    const int quad = lane >> 4;

    floatx4 acc[4][4];
#pragma unroll
    for (int a = 0; a < 4; a++)
#pragma unroll
        for (int b = 0; b < 4; b++) acc[a][b] = (floatx4){0.f, 0.f, 0.f, 0.f};

    const uint16_t* Ab = qkT + (size_t)n * HW * CK;
    const uint16_t* Bb = mkT + (size_t)n * M_ * CK;

#pragma unroll
    for (int kc = 0; kc < 2; kc++) {
        __syncthreads();
#pragma unroll
        for (int j = 0; j < 4; j++) {
            int idx = tid + j * 256;
            int r   = idx >> 3;
            int c8  = (idx & 7) * 8;
            uintx4 v = {0u, 0u, 0u, 0u};
            if (q0 + r < HW) v = *(const uintx4*)&Ab[(size_t)(q0 + r) * CK + kc * 64 + c8];
            *(uintx4*)&ldsA[r * K1_LD + c8] = v;
        }
#pragma unroll
        for (int j = 0; j < 4; j++) {
            int idx = tid + j * 256;
            int r   = idx >> 3;
            int c8  = (idx & 7) * 8;
            uintx4 v = {0u, 0u, 0u, 0u};
            if (m0 + r < M_) v = *(const uintx4*)&Bb[(size_t)(m0 + r) * CK + kc * 64 + c8];
            *(uintx4*)&ldsB[r * K1_LD + c8] = v;
        }
        __syncthreads();
#pragma unroll
        for (int ks = 0; ks < 2; ks++) {
            const int k0 = ks * 32 + quad * 8;
            short8 af[4], bfr[4];
#pragma unroll
            for (int t = 0; t < 4; t++)
                af[t] = *(const short8*)&ldsA[(wq + t * 16 + fr) * K1_LD + k0];
#pragma unroll
            for (int t = 0; t < 4; t++)
                bfr[t] = *(const short8*)&ldsB[(wm + t * 16 + fr) * K1_LD + k0];
#pragma unroll
            for (int tq = 0; tq < 4; tq++)
#pragma unroll
                for (int tm = 0; tm < 4; tm++)
                    acc[tq][tm] = __builtin_amdgcn_mfma_f32_16x16x32_bf16(
                        af[tq], bfr[tm], acc[tq][tm], 0, 0, 0);
        }
    }

    // ---- epilogue phase A: exp -> LDS C-tile (stride 144), colsum
    __syncthreads();   // all frag reads done; smem reusable as C-tile
    float cs[4] = {0.f, 0.f, 0.f, 0.f};
#pragma unroll
    for (int tq = 0; tq < 4; tq++) {
#pragma unroll
        for (int tm = 0; tm < 4; tm++) {
            const int col = wm + tm * 16 + fr;
#pragma unroll
            for (int i = 0; i < 4; i++) {
                const int row = wq + tq * 16 + quad * 4 + i;
                float e = __expf(acc[tq][tm][i] * QK_SCALE);
                if (q0 + row < HW) cs[tm] += e;   // guard: padded q-rows must not pollute colsum
                smem[row * K1_TS + col] = (short)f32_to_bf16(e);
            }
        }
    }
#pragma unroll
    for (int tm = 0; tm < 4; tm++) {
        float s = cs[tm];
        s += __shfl_xor(s, 16, 64);
        s += __shfl_xor(s, 32, 64);
        if (quad == 0) atomicAdd(&colsum[wm + tm * 16 + fr], s);
    }
    __syncthreads();   // C-tile complete + colsum complete

    // ---- epilogue phase B: coalesced uint4 E-writes (8 per thread)
    uint16_t* En = E + (size_t)n * HW * M_;
#pragma unroll
    for (int j = 0; j < 8; j++) {
        int idx = tid + j * 256;       // 0..2047 = 128 rows x 16 uint4
        int r   = idx >> 4;
        int c8  = (idx & 15) * 8;      // short offset in row
        if (q0 + r < HW && m0 + c8 + 8 <= M_) {
            uintx4 v = *(const uintx4*)&smem[r * K1_TS + c8];
            *(uintx4*)&En[(size_t)(q0 + r) * M_ + m0 + c8] = v;
        }
    }
    if (tid < 128) {
        const int gm = m0 + tid;
        if (gm < M_) atomicAdd(&dsum[(size_t)n * M_ + gm], colsum[tid]);
    }
}

// ---------------------------------------------------------------- dinv = 1/d
__global__ void k_dinv(const float* __restrict__ d, float* __restrict__ di) {
    int i = blockIdx.x * 256 + threadIdx.x;
    if (i < N_ * M_) di[i] = 1.0f / d[i];
}

// ---------------------------------------------------------------- mvs = bf16(mv * dinv[m])
__global__ __launch_bounds__(256) void k_mvs(
    const float* __restrict__ mval,   // [N][CV][M]
    const float* __restrict__ dinv,   // [N][M]
    uint16_t* __restrict__ mvs)       // [N][CV][M]
{
    unsigned i = blockIdx.x * 256 + threadIdx.x;
    unsigned base = i * 4u;
    unsigned n = base / (unsigned)(CV * M_);
    unsigned m = base % (unsigned)M_;
    floatx4 v  = *(const floatx4*)&mval[base];
    floatx4 di = *(const floatx4*)&dinv[n * (unsigned)M_ + m];
    ushortx4 o;
    o[0] = f32_to_bf16(v[0] * di[0]);
    o[1] = f32_to_bf16(v[1] * di[1]);
    o[2] = f32_to_bf16(v[2] * di[2]);
    o[3] = f32_to_bf16(v[3] * di[3]);
    *(ushortx4*)&mvs[base] = o;
}

// ---------------------------------------------------------------- K2 split x3 (round-5 verbatim, passing)
#define K2_LD 104     // 96 + 8 pad (shorts)
#define K2_SPLITS 3
#define K2_STEPS 25   // 2400 / 96

__global__ __launch_bounds__(256) void k2_split3(
    const uint16_t* __restrict__ mvs,  // [N][CV][M] bf16
    const uint16_t* __restrict__ E,    // [N][HW][M] bf16
    float* __restrict__ partials)      // [3][N][CV][HW]
{
    __shared__ short ldsA[128 * K2_LD];
    __shared__ short ldsB[128 * K2_LD];

    const int q0 = blockIdx.x * 128;
    const int c0 = blockIdx.y * 128;
    const int nz = blockIdx.z;
    const int n     = nz / K2_SPLITS;
    const int split = nz - n * K2_SPLITS;
    const int tid = threadIdx.x;

    const int lane = tid & 63;
    const int wid  = tid >> 6;
    const int wc   = (wid >> 1) << 6;
    const int wq   = (wid & 1) << 6;
    const int fr   = lane & 15;
    const int quad = lane >> 4;

    floatx4 acc[4][4];
#pragma unroll
    for (int a = 0; a < 4; a++)
#pragma unroll
        for (int b = 0; b < 4; b++) acc[a][b] = (floatx4){0.f, 0.f, 0.f, 0.f};

    const uint16_t* Asrc = mvs + (size_t)(n * CV + c0) * M_ + split * 2400;
    const uint16_t* Bsrc = E + (size_t)n * HW * M_ + split * 2400;

    for (int step = 0; step < K2_STEPS; step++) {
        const int m0 = step * 96;
        __syncthreads();
#pragma unroll
        for (int j = 0; j < 6; j++) {
            int idx = tid + j * 256;
            int r   = idx / 12;
            int c8  = idx - r * 12;
            uintx4 v = *(const uintx4*)&Asrc[(size_t)r * M_ + m0 + c8 * 8];
            *(uintx4*)&ldsA[r * K2_LD + c8 * 8] = v;
        }
#pragma unroll
        for (int j = 0; j < 6; j++) {
            int idx = tid + j * 256;
            int r   = idx / 12;
            int c8  = idx - r * 12;
            uintx4 v = {0u, 0u, 0u, 0u};
            if (q0 + r < HW) v = *(const uintx4*)&Bsrc[(size_t)(q0 + r) * M_ + m0 + c8 * 8];
            *(uintx4*)&ldsB[r * K2_LD + c8 * 8] = v;
        }
        __syncthreads();
#pragma unroll
        for (int ks = 0; ks < 3; ks++) {
            const int k0 = ks * 32 + quad * 8;
            short8 af[4], bfr[4];
#pragma unroll
            for (int t = 0; t < 4; t++)
                af[t] = *(const short8*)&ldsA[(wc + t * 16 + fr) * K2_LD + k0];
#pragma unroll
            for (int t = 0; t < 4; t++)
                bfr[t] = *(const short8*)&ldsB[(wq + t * 16 + fr) * K2_LD + k0];
#pragma unroll
            for (int tc = 0; tc < 4; tc++)
#pragma unroll
                for (int tq = 0; tq < 4; tq++)
                    acc[tc][tq] = __builtin_amdgcn_mfma_f32_16x16x32_bf16(
                        af[tc], bfr[tq], acc[tc][tq], 0, 0, 0);
        }
    }

    float* P = partials + ((size_t)split * N_ + n) * CV * HW;
#pragma unroll
    for (int tc = 0; tc < 4; tc++) {
#pragma unroll
        for (int tq = 0; tq < 4; tq++) {
            const int gq = q0 + wq + tq * 16 + fr;
            if (gq < HW) {
#pragma unroll
                for (int i = 0; i < 4; i++) {
                    const int gc = c0 + wc + tc * 16 + quad * 4 + i;
                    P[(size_t)gc * HW + gq] = acc[tc][tq][i];
                }
            }
        }
    }
}

// ---------------------------------------------------------------- reduce 3 partials -> out mapped half
__global__ __launch_bounds__(256) void k_reduce3(const float* __restrict__ partials,
                                                 float* __restrict__ out) {
    unsigned i = blockIdx.x * 256 + threadIdx.x;
    unsigned e = i * 4u;
    unsigned n = e / (CV * HW);
    unsigned off = e - n * (CV * HW);
    const size_t stride = (size_t)N_ * CV * HW;
    const float* p = partials + (size_t)n * CV * HW + off;
    floatx4 a = *(const floatx4*)&p[0];
    floatx4 b = *(const floatx4*)&p[stride];
    floatx4 c = *(const floatx4*)&p[2 * stride];
    floatx4 s = a + b + c;
    *(floatx4*)&out[(size_t)n * (2 * CV * HW) + CV * HW + off] = s;
}

// ----------------------------------------------------------------
extern "C" void kernel_launch(void* const* d_in, const int* in_sizes, int n_in,
                              void* d_out, int out_size, void* d_ws, size_t ws_size,
                              hipStream_t stream) {
    const float* qkey = (const float*)d_in[0];  // [8][128][900]
    const float* qval = (const float*)d_in[1];  // [8][512][900]
    const float* mkey = (const float*)d_in[2];  // [8][128][7200]
    const float* mval = (const float*)d_in[3];  // [8][512][7200]
    float* out = (float*)d_out;                 // [8][1024][900]

    char* ws = (char*)d_ws;
    // E 103,680,000 | dsum 230,400 | dinv 230,400 | mvs 58,982,400 | partials 44,236,800 = 207,360,000
    // qkT/mkT alias partials (dead before k2_split3 writes partials).
    uint16_t* E        = (uint16_t*)ws;
    float*    dsum     = (float*)(ws + 103680000);
    float*    dinv     = (float*)(ws + 103910400);
    uint16_t* mvs      = (uint16_t*)(ws + 104140800);
    float*    partials = (float*)(ws + 163123200);
    uint16_t* qkT      = (uint16_t*)(ws + 163123200);
    uint16_t* mkT      = (uint16_t*)(ws + 163123200 + 1843200);

    (void)in_sizes; (void)n_in; (void)out_size; (void)ws_size;

    k_zero<<<dim3((N_ * M_ + 255) / 256), 256, 0, stream>>>(dsum);
    k_copy_qval<<<dim3((N_ * CV * HW) / 4 / 256), 256, 0, stream>>>(qval, out);
    k_trans<<<dim3(29, 4, N_), 256, 0, stream>>>(qkey, qkT, HW);
    k_trans<<<dim3(225, 4, N_), 256, 0, stream>>>(mkey, mkT, M_);
    k1_gemm_exp<<<dim3(57, 8, N_), 256, 0, stream>>>(qkT, mkT, E, dsum);
    k_dinv<<<dim3((N_ * M_ + 255) / 256), 256, 0, stream>>>(dsum, dinv);
    k_mvs<<<dim3((N_ * CV * M_) / 4 / 256), 256, 0, stream>>>(mval, dinv, mvs);
    k2_split3<<<dim3(8, 4, N_ * K2_SPLITS), 256, 0, stream>>>(mvs, E, partials);
    k_reduce3<<<dim3((N_ * CV * HW) / 4 / 256), 256, 0, stream>>>(partials, out);
}